// Round 9
// baseline (344.835 us; speedup 1.0000x reference)
//
#include <hip/hip_runtime.h>

// ---------------------------------------------------------------------------
// SAGAN self-attention block, MI355X / gfx950.
// B=4, C=256, H=W=64 (HW=4096), Ck=32.
// v9: k_attn rebuilt as 4-wave / 256-thr blocks, 10.8 KB LDS, ONE lgkm
// barrier per tile.  Wave = (sg: 16 rows, h: m-half); halves keep
// independent flash stats (split-K algebra); PV = own-rows x 128ch via
// wave-pair LDS P buffer; Q/V just-in-time from global (L1).
// Partials: 4 sets = (key-split 2 x half 2) -> same k_merge as v8.
// ---------------------------------------------------------------------------

constexpr int kC   = 256;
constexpr int kHW  = 4096;
constexpr int kB   = 4;
constexpr int kCHW = kC * kHW;

typedef short bf16x8 __attribute__((ext_vector_type(8)));
typedef float f32x4  __attribute__((ext_vector_type(4)));
typedef unsigned short u16;

__device__ __forceinline__ u16 f2bf(float f) {
    union { float f; unsigned u; } v; v.f = f;
    unsigned u = v.u;
    return (u16)((u + 0x7fffu + ((u >> 16) & 1u)) >> 16);  // RNE
}
__device__ __forceinline__ float bf2f(u16 h) {
    union { unsigned u; float f; } v; v.u = ((unsigned)h) << 16;
    return v.f;
}

// ---------------------------------------------------------------------------
// Kernel 1: inverse spectral norms + W -> bf16 hi/lo, A-fragment-packed.
// ---------------------------------------------------------------------------
__global__ __launch_bounds__(1024) void k_sigma(
    const float* __restrict__ fw, const float* __restrict__ fu,
    const float* __restrict__ gw, const float* __restrict__ gu,
    const float* __restrict__ hww, const float* __restrict__ hu,
    float* __restrict__ sig, u16* __restrict__ wh, u16* __restrict__ wl)
{
    const int which = blockIdx.x;
    const float* W = which == 0 ? fw : (which == 1 ? gw : hww);
    const float* U = which == 0 ? fu : (which == 1 ? gu : hu);
    const int O = (which == 2) ? 256 : 32;
    const int t = threadIdx.x;

    __shared__ float par[4][256];
    __shared__ float red[256];
    __shared__ __align__(16) float Vv[256];

    {
        const int i = t & 255, och = t >> 8;
        int olim = O - och * 64; olim = olim < 0 ? 0 : (olim > 64 ? 64 : olim);
        float p = 0.f;
#pragma unroll 8
        for (int oo = 0; oo < olim; ++oo) {
            const int o = och * 64 + oo;
            p += U[o] * W[o * 256 + i];
        }
        par[och][i] = p;
    }
    __syncthreads();
    float t1 = 0.f;
    if (t < 256) {
        t1 = par[0][t] + par[1][t] + par[2][t] + par[3][t];
        red[t] = t1 * t1;
    }
    __syncthreads();
    for (int s = 128; s > 0; s >>= 1) { if (t < s) red[t] += red[t + s]; __syncthreads(); }
    if (t < 256) Vv[t] = t1 / fmaxf(sqrtf(red[0]), 1e-12f);
    __syncthreads();

    {
        const int o = t & 255, ich = t >> 8;
        float q = 0.f;
        if (o < O) {
            const float4* Wr = (const float4*)(W + (size_t)o * 256 + ich * 64);
            const float4* Vr = (const float4*)(&Vv[ich * 64]);
#pragma unroll
            for (int j = 0; j < 16; ++j) {
                const float4 w = Wr[j]; const float4 v = Vr[j];
                q += w.x * v.x + w.y * v.y + w.z * v.z + w.w * v.w;
            }
        }
        par[ich][o] = q;
    }
    __syncthreads();
    if (t < 256) {
        const float t2 = par[0][t] + par[1][t] + par[2][t] + par[3][t];
        red[t] = t2 * t2;
    }
    __syncthreads();
    for (int s = 128; s > 0; s >>= 1) { if (t < s) red[t] += red[t + s]; __syncthreads(); }
    if (t == 0) {
        const float s2 = red[0];
        sig[which] = fmaxf(sqrtf(s2), 1e-12f) / s2;   // 1/sigma
    }

    // ---- W -> bf16 hi/lo, A-fragment-packed ----
    const int nElem = O * 256;
    const int gbase = (which == 0) ? 0 : (which == 1 ? 32 : 64);  // row base
    for (int i = t; i < nElem; i += 1024) {
        const int o = i >> 8, ci = i & 255;
        const int g = gbase + o;
        const int idx = ((g >> 4) * 8 + (ci >> 5)) * 512 + (g & 15) * 32 + (ci & 31);
        const float f = W[i];
        const u16 h = f2bf(f);
        wh[idx] = h;
        wl[idx] = f2bf(f - bf2f(h));
    }
}

// ---------------------------------------------------------------------------
// Kernel 2: all projections as one MFMA GEMM (unchanged from v8).
// ---------------------------------------------------------------------------
__global__ __launch_bounds__(512) void k_proj(
    const float* __restrict__ x,
    const u16* __restrict__ wh, const u16* __restrict__ wl,
    const float* __restrict__ fb, const float* __restrict__ gb,
    const float* __restrict__ hb, const float* __restrict__ sig,
    u16* __restrict__ Kc, u16* __restrict__ Qc, u16* __restrict__ Vb)
{
    __shared__ __align__(16) float xs[256][64];  // 64 KB
    __shared__ float bLDS[320];

    const int t = threadIdx.x;
    const int wave = t >> 6, lane = t & 63;
    const int quad = lane >> 4, l15 = lane & 15;
    const int b = blockIdx.y;
    const int n0 = blockIdx.x * 64;
    const int nch = wave & 3, cohalf = wave >> 2;

    {
        const int r4i = lane >> 4, c16 = lane & 15;
        const float* xg = x + (size_t)b * kCHW + (size_t)r4i * kHW + n0 + c16 * 4;
#pragma unroll
        for (int j = 0; j < 8; ++j) {
            const int cibase = (wave * 8 + j) * 4;
            __builtin_amdgcn_global_load_lds(
                (const __attribute__((address_space(1))) void*)(xg + (size_t)cibase * kHW),
                (__attribute__((address_space(3))) void*)&xs[cibase][0], 16, 0, 0);
        }
    }
    if (t < 320) bLDS[t] = (t < 32) ? fb[t] : (t < 64) ? gb[t - 32] : hb[t - 64];
    __syncthreads();

    const int n = nch * 16 + l15;
    bf16x8 bh[8], bl[8];
#pragma unroll
    for (int s = 0; s < 8; ++s) {
        union { u16 a[8]; bf16x8 v; } H, L;
#pragma unroll
        for (int j = 0; j < 8; ++j) {
            const float v = xs[s * 32 + quad * 8 + j][n];
            const u16 h = f2bf(v);
            H.a[j] = h; L.a[j] = f2bf(v - bf2f(h));
        }
        bh[s] = H.v; bl[s] = L.v;
    }

    const u16* whp = wh + l15 * 32 + quad * 8;
    const u16* wlp = wl + l15 * 32 + quad * 8;

    f32x4 acc[10] = {};
#pragma unroll
    for (int c = 0; c < 10; ++c) {
        const size_t base = (size_t)(cohalf * 10 + c) * 4096;
#pragma unroll
        for (int s = 0; s < 8; ++s) {
            const bf16x8 ah = *(const bf16x8*)(whp + base + s * 512);
            const bf16x8 al = *(const bf16x8*)(wlp + base + s * 512);
            acc[c] = __builtin_amdgcn_mfma_f32_16x16x32_bf16(ah, bh[s], acc[c], 0, 0, 0);
            acc[c] = __builtin_amdgcn_mfma_f32_16x16x32_bf16(ah, bl[s], acc[c], 0, 0, 0);
            acc[c] = __builtin_amdgcn_mfma_f32_16x16x32_bf16(al, bh[s], acc[c], 0, 0, 0);
        }
    }

    const float s0 = sig[0], s1 = sig[1], s2 = sig[2];
#pragma unroll
    for (int c = 0; c < 10; ++c) {
        const int cog0 = (cohalf * 10 + c) * 16;
        const float inv = (cog0 < 32) ? s0 : (cog0 < 64) ? s1 : s2;
#pragma unroll
        for (int r = 0; r < 4; ++r) {
            const int co = cog0 + quad * 4 + r;
            const float v = acc[c][r] * inv + bLDS[co];
            if (co < 64) {
                u16* H = (co < 32) ? Kc : Qc;
                const int d = co & 31;
                const u16 h = f2bf(v);
                const u16 l = f2bf(v - bf2f(h));
                const size_t off = (size_t)(b * kHW + n0 + n) * 64;
                H[off + d] = h;
                H[off + 32 + d] = l;
            } else {
                Vb[((size_t)b * kC + (co - 64)) * kHW + n0 + n] = f2bf(v);
            }
        }
    }
}

// ---------------------------------------------------------------------------
// Kernel 3: flash attention v9.  grid 1024 (XCD-swizzled), 256 thr (4 waves).
// Wave = (sg = wave&1: 16-row score group, h = wave>>1: m-half).
// Per block: 32 rows x 2048 keys (32 tiles of 64 m, key-split mh).
// Scores: 6 MFMA (hi/lo).  Stats independent per (half,row) — split-K.
// PV: own 32 rows x 128 ch (ch-slice = sg) x K=32 (own m-half); P via
// double-buffered wave-pair LDS ([buf][h][32 n][40 m] bf16).  ONE lgkm
// barrier per tile.  Q/V 16B just-in-time global loads (L1-deduped).
// Epilogue: bf16 partial O + (m,l), set = mh*2 + h (4 sets).
// ---------------------------------------------------------------------------
__global__ __launch_bounds__(256, 4) void k_attn(
    const u16* __restrict__ Kc, const u16* __restrict__ Qc,
    const u16* __restrict__ Vb,
    u16* __restrict__ Op, float2* __restrict__ St)
{
    __shared__ __align__(16) u16 Pb[2][2][32][40];   // 10240 B
    __shared__ float aB[2][2][32];                   // 512 B

    const int t = threadIdx.x;
    const int wave = t >> 6, lane = t & 63;
    const int quad = lane >> 4, l15 = lane & 15;
    const int sg = wave & 1, h = wave >> 1;

    const int id = blockIdx.x;
    const int xcd = id & 7;
    const int b = xcd >> 1;
    const int slot = (xcd & 1) * 128 + (id >> 3);   // 0..255
    const int rb = slot & 127, mh = slot >> 7;
    const int nb0 = rb * 32;
    const int mt0 = mh * 32, mt1 = mt0 + 32;

    const u16* Kb  = Kc + (size_t)b * kHW * 64;
    const u16* Qb  = Qc + (size_t)b * kHW * 64;
    const u16* Vbb = Vb + (size_t)b * kC * kHW;

    // K B-frags: cols n = nb0 + sg*16 + l15
    const size_t krow = (size_t)(nb0 + sg * 16 + l15) * 64 + (size_t)quad * 8;
    const bf16x8 kh = *(const bf16x8*)(Kb + krow);
    const bf16x8 kl = *(const bf16x8*)(Kb + krow + 32);

    f32x4 O[16] = {};    // [rt 2][ct 8]: rows rt*16+quad*4+r, ch sg*128+ct*16+l15
    float mrow = -1e30f, lrow = 0.f;

    for (int mt = mt0; mt < mt1; ++mt) {
        const int cur = mt & 1;
        const int m0 = mt * 64;

        // ---- Q A-frags just-in-time: rows m = m0 + h*32 + mi2*16 + l15 ----
        bf16x8 qh[2], ql[2];
#pragma unroll
        for (int mi2 = 0; mi2 < 2; ++mi2) {
            const size_t qoff = (size_t)(m0 + h * 32 + mi2 * 16 + l15) * 64 + quad * 8;
            qh[mi2] = *(const bf16x8*)(Qb + qoff);
            ql[mi2] = *(const bf16x8*)(Qb + qoff + 32);
        }

        // ---- scores: D[row=m local][col=n (sg's 16)] ----
        f32x4 s[2];
#pragma unroll
        for (int mi2 = 0; mi2 < 2; ++mi2) {
            f32x4 a = { 0.f, 0.f, 0.f, 0.f };
            a = __builtin_amdgcn_mfma_f32_16x16x32_bf16(qh[mi2], kl, a, 0, 0, 0);
            a = __builtin_amdgcn_mfma_f32_16x16x32_bf16(ql[mi2], kh, a, 0, 0, 0);
            a = __builtin_amdgcn_mfma_f32_16x16x32_bf16(qh[mi2], kh, a, 0, 0, 0);
            s[mi2] = a;
        }

        // ---- per-lane online stats for row n = sg*16 + l15, half h ----
        float lm = s[0][0];
#pragma unroll
        for (int mi2 = 0; mi2 < 2; ++mi2)
#pragma unroll
            for (int r = 0; r < 4; ++r) lm = fmaxf(lm, s[mi2][r]);
        lm = fmaxf(lm, __shfl_xor(lm, 16));
        lm = fmaxf(lm, __shfl_xor(lm, 32));
        const float mnew = fmaxf(mrow, lm);
        const float alpha = __expf(mrow - mnew);
        float ls = 0.f;
#pragma unroll
        for (int mi2 = 0; mi2 < 2; ++mi2)
#pragma unroll
            for (int r = 0; r < 4; ++r) {
                const float p = __expf(s[mi2][r] - mnew);
                s[mi2][r] = p;
                ls += p;
            }
        ls += __shfl_xor(ls, 16);
        ls += __shfl_xor(ls, 32);
        lrow = lrow * alpha + ls;
        mrow = mnew;

        // ---- write P ([h][n][m local], pad 40) + alpha ----
        {
            u16* Pw = &Pb[cur][h][sg * 16 + l15][0];
#pragma unroll
            for (int mi2 = 0; mi2 < 2; ++mi2) {
                const unsigned d0 = __builtin_amdgcn_perm(
                    __float_as_uint(s[mi2][1]), __float_as_uint(s[mi2][0]), 0x07060302u);
                const unsigned d1 = __builtin_amdgcn_perm(
                    __float_as_uint(s[mi2][3]), __float_as_uint(s[mi2][2]), 0x07060302u);
                *(uint2*)(Pw + mi2 * 16 + quad * 4) = make_uint2(d0, d1);
            }
            if (lane < 16) aB[cur][h][sg * 16 + l15] = alpha;
        }

        // ---- the ONE barrier: P/alpha visibility (lgkm only) ----
        asm volatile("s_waitcnt lgkmcnt(0)\n\ts_barrier" ::: "memory");

        // ---- rescale O by per-row alphas of half h ----
#pragma unroll
        for (int rt = 0; rt < 2; ++rt) {
            const float4 af = *(const float4*)&aB[cur][h][rt * 16 + quad * 4];
#pragma unroll
            for (int ct = 0; ct < 8; ++ct) {
                O[rt * 8 + ct][0] *= af.x;
                O[rt * 8 + ct][1] *= af.y;
                O[rt * 8 + ct][2] *= af.z;
                O[rt * 8 + ct][3] *= af.w;
            }
        }

        // ---- PV: O[32 n][128 ch] += P[32 n][32 m] @ V^T[32 m][128 ch] ----
        const int vmb = m0 + h * 32 + quad * 8;
#pragma unroll
        for (int rt = 0; rt < 2; ++rt) {
            const bf16x8 pa = *(const bf16x8*)&Pb[cur][h][rt * 16 + l15][quad * 8];
#pragma unroll
            for (int ct = 0; ct < 8; ++ct) {
                const bf16x8 vb8 = *(const bf16x8*)(
                    Vbb + (size_t)(sg * 128 + ct * 16 + l15) * kHW + vmb);
                O[rt * 8 + ct] = __builtin_amdgcn_mfma_f32_16x16x32_bf16(
                    pa, vb8, O[rt * 8 + ct], 0, 0, 0);
            }
        }
    }

    // ---- epilogue: partial set = mh*2 + h ----
    const int set = mh * 2 + h;
    if (lane < 16)
        St[(size_t)(set * 4 + b) * kHW + nb0 + sg * 16 + l15] = make_float2(mrow, lrow);

    u16* Opb = Op + (size_t)(set * 4 + b) * kHW * 256;
#pragma unroll
    for (int rt = 0; rt < 2; ++rt) {
#pragma unroll
        for (int ct = 0; ct < 8; ++ct) {
#pragma unroll
            for (int r = 0; r < 4; ++r) {
                const int nn = nb0 + rt * 16 + quad * 4 + r;
                const int c = sg * 128 + ct * 16 + l15;
                Opb[(size_t)nn * 256 + c] = f2bf(O[rt * 8 + ct][r]);
            }
        }
    }
}

// ---------------------------------------------------------------------------
// Kernel 4: merge the four partial sets + epilogue (unchanged from v8).
// ---------------------------------------------------------------------------
__global__ __launch_bounds__(256) void k_merge(
    const float* __restrict__ x, const float* __restrict__ gamma,
    const u16* __restrict__ Op, const float2* __restrict__ St,
    float* __restrict__ out)
{
    const int tid = blockIdx.x * 256 + threadIdx.x;
    const int cg = tid & 31;
    const int n  = (tid >> 5) & 4095;
    const int b  = tid >> 17;
    const int c0 = cg * 8;

    float2 st[4];
#pragma unroll
    for (int q = 0; q < 4; ++q) st[q] = St[(size_t)(q * 4 + b) * kHW + n];
    float M = st[0].x;
#pragma unroll
    for (int q = 1; q < 4; ++q) M = fmaxf(M, st[q].x);
    float w[4], L = 0.f;
#pragma unroll
    for (int q = 0; q < 4; ++q) { w[q] = __expf(st[q].x - M); L += st[q].y * w[q]; }
    const float invL = 1.f / L;
#pragma unroll
    for (int q = 0; q < 4; ++q) w[q] *= invL;
    const float g = gamma[0];

    const size_t base = ((size_t)b * kHW + n) * 256 + c0;
    uint4 A[4];
#pragma unroll
    for (int q = 0; q < 4; ++q)
        A[q] = *(const uint4*)(Op + base + (size_t)q * 4 * kHW * 256);
    const float4 x0 = *(const float4*)(x + base);
    const float4 x1 = *(const float4*)(x + base + 4);

    float o[8];
#pragma unroll
    for (int j = 0; j < 8; ++j) {
        float acc = 0.f;
#pragma unroll
        for (int q = 0; q < 4; ++q) {
            const unsigned word = (j >> 1) == 0 ? A[q].x : (j >> 1) == 1 ? A[q].y
                                 : (j >> 1) == 2 ? A[q].z : A[q].w;
            acc += bf2f((u16)(word >> ((j & 1) * 16))) * w[q];
        }
        o[j] = acc;
    }
    float4 r0, r1;
    r0.x = g * o[0] + x0.x; r0.y = g * o[1] + x0.y;
    r0.z = g * o[2] + x0.z; r0.w = g * o[3] + x0.w;
    r1.x = g * o[4] + x1.x; r1.y = g * o[5] + x1.y;
    r1.z = g * o[6] + x1.z; r1.w = g * o[7] + x1.w;
    *(float4*)(out + base)     = r0;
    *(float4*)(out + base + 4) = r1;
}

// ---------------------------------------------------------------------------
extern "C" void kernel_launch(void* const* d_in, const int* in_sizes, int n_in,
                              void* d_out, int out_size, void* d_ws, size_t ws_size,
                              hipStream_t stream)
{
    const float* x     = (const float*)d_in[0];
    const float* fw    = (const float*)d_in[1];
    const float* fb    = (const float*)d_in[2];
    const float* fu    = (const float*)d_in[3];
    const float* gw    = (const float*)d_in[4];
    const float* gb    = (const float*)d_in[5];
    const float* gu    = (const float*)d_in[6];
    const float* hww   = (const float*)d_in[7];
    const float* hb    = (const float*)d_in[8];
    const float* hu    = (const float*)d_in[9];
    const float* gamma = (const float*)d_in[10];
    float* out = (float*)d_out;

    char* ws = (char*)d_ws;
    float* sig = (float*)ws;                        // 3 floats
    u16* wh = (u16*)(ws + 1024);                    // packed 320x256 bf16 hi
    u16* wl = wh + 320 * 256;                       // packed lo
    u16* Kc = (u16*)(ws + (1u << 20));              // 2 MB
    u16* Qc = (u16*)(ws + (3u << 20));              // 2 MB
    u16* Vb = (u16*)(ws + (5u << 20));              // 8 MB
    u16* Op = (u16*)(ws + (16u << 20));             // 32 MB: [4][4][4096][256] bf16
    float2* St = (float2*)(ws + (48u << 20));       // 512 KB: [4][4][4096]

    k_sigma<<<dim3(3), dim3(1024), 0, stream>>>(fw, fu, gw, gu, hww, hu, sig, wh, wl);
    k_proj<<<dim3(64, 4), dim3(512), 0, stream>>>(x, wh, wl, fb, gb, hb, sig,
                                                  Kc, Qc, Vb);
    k_attn<<<dim3(1024), dim3(256), 0, stream>>>(Kc, Qc, Vb, Op, St);
    k_merge<<<dim3(2048), dim3(256), 0, stream>>>(x, gamma, Op, St, out);
}